// Round 6
// baseline (1381.470 us; speedup 1.0000x reference)
//
#include <hip/hip_runtime.h>

#define NN 6144
#define EE 98304
#define HH 256
#define NHEADS 4
#define NEXP 8
#define SS 400
#define VV 1024
#define TT 768

// ---------------- helpers ----------------
__device__ __forceinline__ float wave_allsum(float v){
  #pragma unroll
  for (int off=32; off; off>>=1) v += __shfl_xor(v, off, 64);
  return v;
}
__device__ __forceinline__ float wave_allmax(float v){
  #pragma unroll
  for (int off=32; off; off>>=1) v = fmaxf(v, __shfl_xor(v, off, 64));
  return v;
}
// 256-thread block sum, broadcast to all threads. red = shared float[4].
__device__ __forceinline__ float block_allsum(float v, float* red){
  int t = threadIdx.x;
  v = wave_allsum(v);
  __syncthreads();
  if ((t & 63) == 0) red[t >> 6] = v;
  __syncthreads();
  return red[0] + red[1] + red[2] + red[3];
}
__device__ __forceinline__ float gelu_exact(float x){
  return 0.5f * x * (1.0f + erff(x * 0.70710678118654752f));
}
__device__ __forceinline__ float leaky02(float x){
  return x >= 0.f ? x : 0.2f * x;
}

// ---------------- generic f32 GEMM: C[M,N] = (ACC? C:0) + A[M,K]@B[K,N] ----------------
template<bool ACC>
__global__ __launch_bounds__(256) void gemm_f32(const float* __restrict__ A,
    const float* __restrict__ B, float* __restrict__ C, int M, int Nc, int K){
  __shared__ float As[16][65];
  __shared__ float Bs[16][64];
  int t = threadIdx.x;
  int tx = t & 15, ty = t >> 4;
  int m0 = blockIdx.y * 64, n0 = blockIdx.x * 64;
  float acc[4][4] = {};
  for (int k0 = 0; k0 < K; k0 += 16){
    int ca = t & 15, ra = t >> 4;
    #pragma unroll
    for (int p = 0; p < 4; p++)
      As[ca][ra + p*16] = A[(size_t)(m0 + ra + p*16) * K + k0 + ca];
    int nb = t & 63, kb = t >> 6;
    #pragma unroll
    for (int p = 0; p < 4; p++)
      Bs[kb + p*4][nb] = B[(size_t)(k0 + kb + p*4) * Nc + n0 + nb];
    __syncthreads();
    #pragma unroll
    for (int kk = 0; kk < 16; kk++){
      float a[4], b[4];
      #pragma unroll
      for (int i = 0; i < 4; i++) a[i] = As[kk][ty*4 + i];
      #pragma unroll
      for (int j = 0; j < 4; j++) b[j] = Bs[kk][tx*4 + j];
      #pragma unroll
      for (int i = 0; i < 4; i++)
        #pragma unroll
        for (int j = 0; j < 4; j++) acc[i][j] += a[i] * b[j];
    }
    __syncthreads();
  }
  #pragma unroll
  for (int i = 0; i < 4; i++){
    int m = m0 + ty*4 + i;
    #pragma unroll
    for (int j = 0; j < 4; j++){
      int n = n0 + tx*4 + j;
      size_t idx = (size_t)m * Nc + n;
      C[idx] = (ACC ? C[idx] : 0.0f) + acc[i][j];
    }
  }
}

// ---------------- x finalize: x = mask ? mask_token : 0.5*(tmp + bv + bt) ----------------
__global__ void xfin_kernel(const float* __restrict__ tmp, const float* __restrict__ pvb,
                            const float* __restrict__ ptb, const float* __restrict__ mtok,
                            const int* __restrict__ mask_int, float* __restrict__ x){
  int i = blockIdx.x * 256 + threadIdx.x;
  int n = i >> 8, j = i & 255;
  bool m = (mask_int[n] == 0);
  x[i] = m ? mtok[j] : 0.5f * (tmp[i] + pvb[j] + ptb[j]);
}

__global__ void mlist_kernel(const int* __restrict__ mask_int, int* mlist, int* mcount){
  int n = blockIdx.x * 256 + threadIdx.x;
  if (n < NN && mask_int[n] == 0){
    int p = atomicAdd(mcount, 1);
    mlist[p] = n;
  }
}

// ---------------- gate: softmax over 8, top-2 ----------------
__global__ __launch_bounds__(256) void gate_topk_kernel(const float* __restrict__ x,
    const float* __restrict__ gw, const float* __restrict__ gb,
    int* __restrict__ ti, float* __restrict__ twt){
  int n = blockIdx.x, t = threadIdx.x;
  __shared__ float sx[256];
  __shared__ float logits[8];
  sx[t] = x[(size_t)n*256 + t];
  __syncthreads();
  int e = t >> 5, lane = t & 31;
  float p = 0.f;
  for (int h2 = lane; h2 < 256; h2 += 32) p += sx[h2] * gw[h2*8 + e];
  #pragma unroll
  for (int off = 16; off; off >>= 1) p += __shfl_down(p, off, 32);
  if (lane == 0) logits[e] = p + gb[e];
  __syncthreads();
  if (t == 0){
    float mx = -3.0e38f;
    #pragma unroll
    for (int i = 0; i < 8; i++) mx = fmaxf(mx, logits[i]);
    float g[8], s = 0.f;
    #pragma unroll
    for (int i = 0; i < 8; i++){ g[i] = expf(logits[i] - mx); s += g[i]; }
    #pragma unroll
    for (int i = 0; i < 8; i++) g[i] /= s;
    int i0 = 0;
    for (int i = 1; i < 8; i++) if (g[i] > g[i0]) i0 = i;
    int i1 = (i0 == 0) ? 1 : 0;
    for (int i = 0; i < 8; i++) if (i != i0 && g[i] > g[i1]) i1 = i;
    float w0 = g[i0], w1 = g[i1], sw = w0 + w1;
    ti[n*2] = i0; ti[n*2+1] = i1;
    twt[n*2] = w0 / sw; twt[n*2+1] = w1 / sw;
  }
}

// ---------------- MoE: per node, 2 selected experts (GEMV+LN+GELU+GEMV) ----------------
__global__ __launch_bounds__(256) void moe_kernel(const float* __restrict__ x,
    const int* __restrict__ ti, const float* __restrict__ twt,
    const float* __restrict__ w1, const float* __restrict__ b1,
    const float* __restrict__ lng, const float* __restrict__ lnb,
    const float* __restrict__ w2, const float* __restrict__ b2,
    float* __restrict__ h){
  int n = blockIdx.x, t = threadIdx.x;
  __shared__ float sx[256], sh[256];
  __shared__ float red[4];
  sx[t] = x[(size_t)n*256 + t];
  float acc = 0.f;
  for (int k = 0; k < 2; k++){
    int e = ti[n*2 + k];
    float wgt = twt[n*2 + k];
    const float* W1 = w1 + (size_t)e * 65536;
    const float* W2 = w2 + (size_t)e * 65536;
    __syncthreads();
    float s = b1[e*256 + t];
    for (int hh = 0; hh < 256; hh++) s += sx[hh] * W1[hh*256 + t];
    float mean = block_allsum(s, red) * (1.f/256.f);
    float d = s - mean;
    float var = block_allsum(d*d, red) * (1.f/256.f);
    float nrm = d * rsqrtf(var + 1e-5f) * lng[e*256 + t] + lnb[e*256 + t];
    float ge = gelu_exact(nrm);
    __syncthreads();
    sh[t] = ge;
    __syncthreads();
    float o = b2[e*256 + t];
    for (int kk = 0; kk < 256; kk++) o += sh[kk] * W2[kk*256 + t];
    acc += wgt * o;
  }
  h[(size_t)n*256 + t] = acc;
}

// ---------------- CSR build ----------------
__global__ void csr_count(const int* __restrict__ dst, int* counts){
  int e = blockIdx.x * 256 + threadIdx.x;
  if (e < EE) atomicAdd(&counts[dst[e]], 1);
}
__global__ __launch_bounds__(1024) void csr_scan(const int* __restrict__ counts, int* offs){
  __shared__ int part[1024];
  int t = threadIdx.x;
  int base = t * 6;
  int c[6]; int s = 0;
  #pragma unroll
  for (int q = 0; q < 6; q++){ c[q] = counts[base + q]; s += c[q]; }
  part[t] = s;
  __syncthreads();
  for (int off = 1; off < 1024; off <<= 1){
    int add = (t >= off) ? part[t - off] : 0;
    __syncthreads();
    part[t] += add;
    __syncthreads();
  }
  int excl = (t == 0) ? 0 : part[t-1];
  #pragma unroll
  for (int q = 0; q < 6; q++){ offs[base + q] = excl; excl += c[q]; }
  if (t == 1023) offs[NN] = excl;
}
__global__ void csr_fill(const int* __restrict__ src, const int* __restrict__ dst,
                         const int* __restrict__ offs, int* cursors, int* esrc){
  int e = blockIdx.x * 256 + threadIdx.x;
  if (e < EE){
    int d = dst[e];
    int pos = offs[d] + atomicAdd(&cursors[d], 1);
    esrc[pos] = src[e];
  }
}

// ---------------- GAT: el/er ----------------
__global__ __launch_bounds__(256) void eler_kernel(const float* __restrict__ z,
    const float* __restrict__ al, const float* __restrict__ ar,
    float* __restrict__ el, float* __restrict__ er){
  int n = blockIdx.x, t = threadIdx.x;
  int hd = t >> 6, lane = t & 63;
  const float* zr = z + (size_t)n*1024 + hd*256;
  float pl = 0.f, pr = 0.f;
  #pragma unroll
  for (int q = 0; q < 4; q++){
    int j = lane + q*64;
    float zv = zr[j];
    pl += zv * al[hd*256 + j];
    pr += zv * ar[hd*256 + j];
  }
  pl = wave_allsum(pl);
  pr = wave_allsum(pr);
  if (lane == 0){ el[n*4 + hd] = pl; er[n*4 + hd] = pr; }
}

// ---------------- GAT: per-dst softmax-aggregate ----------------
__global__ __launch_bounds__(256) void gat_agg(const float* __restrict__ z,
    const float* __restrict__ el, const float* __restrict__ er,
    const int* __restrict__ offs, const int* __restrict__ esrc,
    const float* __restrict__ bias, float* __restrict__ hout){
  int n = blockIdx.x, t = threadIdx.x;
  int beg = offs[n], end = offs[n+1], deg = end - beg;
  __shared__ float ser[4];
  __shared__ float rbuf[4][4];
  __shared__ float smax[4], sden[4];
  __shared__ int ssrc[64];
  __shared__ float sal[64][4];
  if (t < 4) ser[t] = er[n*4 + t];
  __syncthreads();
  float acc4[4] = {0.f, 0.f, 0.f, 0.f};
  if (deg > 0){
    // pass 1: per-head max
    float mx[4] = {-3.0e38f, -3.0e38f, -3.0e38f, -3.0e38f};
    for (int i = t; i < deg; i += 256){
      int s = esrc[beg + i];
      #pragma unroll
      for (int hd = 0; hd < 4; hd++){
        float ev = leaky02(el[s*4 + hd] + ser[hd]);
        mx[hd] = fmaxf(mx[hd], ev);
      }
    }
    #pragma unroll
    for (int hd = 0; hd < 4; hd++) mx[hd] = wave_allmax(mx[hd]);
    if ((t & 63) == 0){
      #pragma unroll
      for (int hd = 0; hd < 4; hd++) rbuf[t >> 6][hd] = mx[hd];
    }
    __syncthreads();
    if (t < 4) smax[t] = fmaxf(fmaxf(rbuf[0][t], rbuf[1][t]), fmaxf(rbuf[2][t], rbuf[3][t]));
    __syncthreads();
    // pass 2: sum of exp
    float sum_[4] = {0.f, 0.f, 0.f, 0.f};
    for (int i = t; i < deg; i += 256){
      int s = esrc[beg + i];
      #pragma unroll
      for (int hd = 0; hd < 4; hd++){
        float ev = leaky02(el[s*4 + hd] + ser[hd]);
        sum_[hd] += expf(ev - smax[hd]);
      }
    }
    #pragma unroll
    for (int hd = 0; hd < 4; hd++) sum_[hd] = wave_allsum(sum_[hd]);
    if ((t & 63) == 0){
      #pragma unroll
      for (int hd = 0; hd < 4; hd++) rbuf[t >> 6][hd] = sum_[hd];
    }
    __syncthreads();
    if (t < 4){
      float den = rbuf[0][t] + rbuf[1][t] + rbuf[2][t] + rbuf[3][t];
      sden[t] = (den > 0.f) ? 1.f / den : 1.f;
    }
    __syncthreads();
    // pass 3: chunked alpha * z[src]
    for (int base = 0; base < deg; base += 64){
      int cnt = min(64, deg - base);
      __syncthreads();
      if (t < cnt){
        int s = esrc[beg + base + t];
        ssrc[t] = s;
        #pragma unroll
        for (int hd = 0; hd < 4; hd++){
          float ev = leaky02(el[s*4 + hd] + ser[hd]);
          sal[t][hd] = expf(ev - smax[hd]) * sden[hd];
        }
      }
      __syncthreads();
      for (int i = 0; i < cnt; i++){
        const float* zp = z + (size_t)ssrc[i] * 1024;
        #pragma unroll
        for (int hd = 0; hd < 4; hd++) acc4[hd] += sal[i][hd] * zp[hd*256 + t];
      }
    }
  }
  float o = 0.f;
  #pragma unroll
  for (int hd = 0; hd < 4; hd++) o += acc4[hd] + bias[hd*256 + t];
  hout[(size_t)n*256 + t] = 0.25f * o;
}

// ---------------- recon loss for masked nodes (fused decode + cosine + focal) ----------------
__global__ __launch_bounds__(256) void rec_kernel(const float* __restrict__ h,
    const int* __restrict__ mlist, const int* __restrict__ mcount,
    const float* __restrict__ w1, const float* __restrict__ b1,
    const float* __restrict__ g, const float* __restrict__ bb,
    const float* __restrict__ w2, const float* __restrict__ b2,
    const float* __restrict__ tgt, int Vd, float* __restrict__ acc_out){
  int idx = blockIdx.x;
  if (idx >= *mcount) return;
  int n = mlist[idx];
  int t = threadIdx.x;
  __shared__ float sx[256], sh[256];
  __shared__ float red[4];
  sx[t] = h[(size_t)n*256 + t];
  __syncthreads();
  float s = b1[t];
  for (int hh = 0; hh < 256; hh++) s += sx[hh] * w1[hh*256 + t];
  float mean = block_allsum(s, red) * (1.f/256.f);
  float d = s - mean;
  float var = block_allsum(d*d, red) * (1.f/256.f);
  float nrm = d * rsqrtf(var + 1e-5f) * g[t] + bb[t];
  float ge = gelu_exact(nrm);
  __syncthreads();
  sh[t] = ge;
  __syncthreads();
  float dot = 0.f, nr = 0.f, nt = 0.f;
  for (int j = t; j < Vd; j += 256){
    float r = b2[j];
    for (int k = 0; k < 256; k++) r += sh[k] * w2[(size_t)k*Vd + j];
    float tg = tgt[(size_t)n*Vd + j];
    dot += r * tg; nr += r * r; nt += tg * tg;
  }
  dot = block_allsum(dot, red);
  __syncthreads();
  nr = block_allsum(nr, red);
  __syncthreads();
  nt = block_allsum(nt, red);
  if (t == 0){
    float sim = dot / (fmaxf(sqrtf(nr), 1e-8f) * fmaxf(sqrtf(nt), 1e-8f));
    float f = 1.f - sim;
    atomicAdd(acc_out, f * f);
  }
}

// ---------------- SPD: li/lj ----------------
__global__ __launch_bounds__(256) void spd_lin_kernel(const float* __restrict__ h,
    const int* __restrict__ sidx, const float* __restrict__ w1,
    float* __restrict__ li, float* __restrict__ lj){
  int i = blockIdx.x, t = threadIdx.x;
  __shared__ float sx[256];
  int n = sidx[i];
  sx[t] = h[(size_t)n*256 + t];
  __syncthreads();
  float a = 0.f, b = 0.f;
  for (int hh = 0; hh < 256; hh++){
    float xv = sx[hh];
    a += xv * w1[hh*256 + t];
    b += xv * w1[(256 + hh)*256 + t];
  }
  li[i*256 + t] = a;
  lj[i*256 + t] = b;
}

// ---------------- SPD: pairwise LN+GELU+dot, MSE accumulate ----------------
__global__ __launch_bounds__(256) void spd_pair_kernel(const float* __restrict__ li,
    const float* __restrict__ lj, const float* __restrict__ b1,
    const float* __restrict__ lng, const float* __restrict__ lnb,
    const float* __restrict__ w2, const float* __restrict__ b2,
    const float* __restrict__ spd, const int* __restrict__ sidx,
    float* __restrict__ buckets){
  int wid = threadIdx.x >> 6, lane = threadIdx.x & 63;
  int pair = blockIdx.x * 4 + wid;
  int i = pair / SS, j = pair % SS;
  __shared__ float bsum[4];
  float v[4];
  float tot = 0.f;
  #pragma unroll
  for (int q = 0; q < 4; q++){
    int c = lane + q*64;
    v[q] = li[i*256 + c] + lj[j*256 + c] + b1[c];
    tot += v[q];
  }
  tot = wave_allsum(tot);
  float mean = tot * (1.f/256.f);
  float var = 0.f;
  #pragma unroll
  for (int q = 0; q < 4; q++){ float d = v[q] - mean; var += d*d; }
  var = wave_allsum(var) * (1.f/256.f);
  float rstd = rsqrtf(var + 1e-5f);
  float dotp = 0.f;
  #pragma unroll
  for (int q = 0; q < 4; q++){
    int c = lane + q*64;
    float nrm = (v[q] - mean) * rstd * lng[c] + lnb[c];
    dotp += gelu_exact(nrm) * w2[c];
  }
  dotp = wave_allsum(dotp);
  float contrib = 0.f;
  if (lane == 0){
    float pred = dotp + b2[0];
    float st = spd[(size_t)sidx[i] * NN + sidx[j]];
    float diff = pred - st;
    contrib = diff * diff;
  }
  if (lane == 0) bsum[wid] = contrib;
  __syncthreads();
  if (threadIdx.x == 0){
    float s = bsum[0] + bsum[1] + bsum[2] + bsum[3];
    atomicAdd(&buckets[blockIdx.x & 255], s);
  }
}

// ---------------- finalize ----------------
__global__ __launch_bounds__(256) void finalize_kernel(const float* __restrict__ rec_acc,
    const float* __restrict__ buckets, const int* __restrict__ mcount,
    float* __restrict__ out){
  __shared__ float red[4];
  int t = threadIdx.x;
  float v = buckets[t];
  float spd_sum = block_allsum(v, red);
  if (t == 0){
    float nm = fmaxf((float)(*mcount), 1.0f);
    out[0] = rec_acc[0] / nm + 0.5f * (spd_sum / (float)(SS * SS));
  }
}

__global__ void copy_h_kernel(const float* __restrict__ h, float* __restrict__ out){
  int i = blockIdx.x * 256 + threadIdx.x;
  out[1 + i] = h[i];
}

// ---------------- launch ----------------
extern "C" void kernel_launch(void* const* d_in, const int* in_sizes, int n_in,
                              void* d_out, int out_size, void* d_ws, size_t ws_size,
                              hipStream_t stream){
  const float* feat_v   = (const float*)d_in[0];
  const float* feat_t   = (const float*)d_in[1];
  const float* spd_mat  = (const float*)d_in[2];
  const float* proj_v_w = (const float*)d_in[3];
  const float* proj_v_b = (const float*)d_in[4];
  const float* proj_t_w = (const float*)d_in[5];
  const float* proj_t_b = (const float*)d_in[6];
  const float* mask_tok = (const float*)d_in[7];
  const float* gate_w   = (const float*)d_in[8];
  const float* gate_b   = (const float*)d_in[9];
  const float* moe_w1   = (const float*)d_in[10];
  const float* moe_b1   = (const float*)d_in[11];
  const float* moe_lng  = (const float*)d_in[12];
  const float* moe_lnb  = (const float*)d_in[13];
  const float* moe_w2   = (const float*)d_in[14];
  const float* moe_b2   = (const float*)d_in[15];
  const float* gat_fc   = (const float*)d_in[16];
  const float* gat_al   = (const float*)d_in[17];
  const float* gat_ar   = (const float*)d_in[18];
  const float* gat_bias = (const float*)d_in[19];
  const float* dv_w1 = (const float*)d_in[20];
  const float* dv_b1 = (const float*)d_in[21];
  const float* dv_g  = (const float*)d_in[22];
  const float* dv_b  = (const float*)d_in[23];
  const float* dv_w2 = (const float*)d_in[24];
  const float* dv_b2 = (const float*)d_in[25];
  const float* dt_w1 = (const float*)d_in[26];
  const float* dt_b1 = (const float*)d_in[27];
  const float* dt_g  = (const float*)d_in[28];
  const float* dt_b  = (const float*)d_in[29];
  const float* dt_w2 = (const float*)d_in[30];
  const float* dt_b2 = (const float*)d_in[31];
  const float* spd_w1 = (const float*)d_in[32];
  const float* spd_b1 = (const float*)d_in[33];
  const float* spd_g  = (const float*)d_in[34];
  const float* spd_bb = (const float*)d_in[35];
  const float* spd_w2 = (const float*)d_in[36];
  const float* spd_b2 = (const float*)d_in[37];
  const int* src      = (const int*)d_in[38];
  const int* dst      = (const int*)d_in[39];
  const int* mask_int = (const int*)d_in[40];
  const int* sidx     = (const int*)d_in[41];

  // workspace carve (256B aligned)
  char* ws = (char*)d_ws;
  size_t off = 0;
  auto carve = [&](size_t bytes) -> char* {
    char* p = ws + off;
    off = (off + bytes + 255) & ~(size_t)255;
    return p;
  };
  // control block (memset to 0 each launch)
  int* counts  = (int*)carve(NN * 4);
  int* cursors = (int*)carve(NN * 4);
  int* offs    = (int*)carve((NN + 1) * 4);
  int* mlist   = (int*)carve(NN * 4);
  int* mcount  = (int*)carve(4);
  float* rec_acc = (float*)carve(4);
  float* buckets = (float*)carve(256 * 4);
  int* esrc    = (int*)carve(EE * 4);
  int* ti      = (int*)carve(NN * 2 * 4);
  size_t ctl_bytes = off;  // zero everything up to here (ti harmlessly included)
  float* twt = (float*)carve(NN * 2 * 4);
  float* tmp = (float*)carve((size_t)NN * HH * 4);
  float* x   = (float*)carve((size_t)NN * HH * 4);
  float* hA  = (float*)carve((size_t)NN * HH * 4);
  float* hB  = (float*)carve((size_t)NN * HH * 4);
  float* z   = (float*)carve((size_t)NN * NHEADS * HH * 4);
  float* el  = (float*)carve((size_t)NN * NHEADS * 4);
  float* er  = (float*)carve((size_t)NN * NHEADS * 4);
  float* li  = (float*)carve((size_t)SS * HH * 4);
  float* lj  = (float*)carve((size_t)SS * HH * 4);
  (void)ws_size; (void)in_sizes; (void)n_in; (void)out_size;

  hipMemsetAsync(ws, 0, ctl_bytes, stream);

  // projection: tmp = feat_v@Wv + feat_t@Wt ; x = mask? token : 0.5*(tmp+bv+bt)
  gemm_f32<false><<<dim3(HH/64, NN/64), 256, 0, stream>>>(feat_v, proj_v_w, tmp, NN, HH, VV);
  gemm_f32<true ><<<dim3(HH/64, NN/64), 256, 0, stream>>>(feat_t, proj_t_w, tmp, NN, HH, TT);
  xfin_kernel<<<NN * HH / 256, 256, 0, stream>>>(tmp, proj_v_b, proj_t_b, mask_tok, mask_int, x);
  mlist_kernel<<<NN / 256, 256, 0, stream>>>(mask_int, mlist, mcount);

  // MoE
  gate_topk_kernel<<<NN, 256, 0, stream>>>(x, gate_w, gate_b, ti, twt);
  moe_kernel<<<NN, 256, 0, stream>>>(x, ti, twt, moe_w1, moe_b1, moe_lng, moe_lnb,
                                     moe_w2, moe_b2, hA);

  // CSR by dst (static across layers)
  csr_count<<<EE / 256, 256, 0, stream>>>(dst, counts);
  csr_scan<<<1, 1024, 0, stream>>>(counts, offs);
  csr_fill<<<EE / 256, 256, 0, stream>>>(src, dst, offs, cursors, esrc);

  // GAT layers
  float* hin = hA; float* hout_ = hB;
  for (int l = 0; l < 3; l++){
    gemm_f32<false><<<dim3(NHEADS*HH/64, NN/64), 256, 0, stream>>>(
        hin, gat_fc + (size_t)l * HH * NHEADS * HH, z, NN, NHEADS*HH, HH);
    eler_kernel<<<NN, 256, 0, stream>>>(z, gat_al + (size_t)l * NHEADS * HH,
                                        gat_ar + (size_t)l * NHEADS * HH, el, er);
    gat_agg<<<NN, 256, 0, stream>>>(z, el, er, offs, esrc,
                                    gat_bias + (size_t)l * NHEADS * HH, hout_);
    float* sw = hin; hin = hout_; hout_ = sw;
  }
  // hin now holds final h

  // recon losses (masked nodes only)
  rec_kernel<<<NN, 256, 0, stream>>>(hin, mlist, mcount, dv_w1, dv_b1, dv_g, dv_b,
                                     dv_w2, dv_b2, feat_v, VV, rec_acc);
  rec_kernel<<<NN, 256, 0, stream>>>(hin, mlist, mcount, dt_w1, dt_b1, dt_g, dt_b,
                                     dt_w2, dt_b2, feat_t, TT, rec_acc);

  // SPD loss
  spd_lin_kernel<<<SS, 256, 0, stream>>>(hin, sidx, spd_w1, li, lj);
  spd_pair_kernel<<<SS * SS / 4, 256, 0, stream>>>(li, lj, spd_b1, spd_g, spd_bb,
                                                   spd_w2, spd_b2, spd_mat, sidx, buckets);

  finalize_kernel<<<1, 256, 0, stream>>>(rec_acc, buckets, mcount, (float*)d_out);
  copy_h_kernel<<<NN * HH / 256, 256, 0, stream>>>(hin, (float*)d_out);
}

// Round 7
// 1180.615 us; speedup vs baseline: 1.1701x; 1.1701x over previous
//
#include <hip/hip_runtime.h>

#define NN 6144
#define EE 98304
#define HH 256
#define NHEADS 4
#define NEXP 8
#define SS 400
#define VV 1024
#define TT 768

typedef __bf16 bf16x8 __attribute__((ext_vector_type(8)));
typedef float f32x4 __attribute__((ext_vector_type(4)));
typedef unsigned short u16x8 __attribute__((ext_vector_type(8)));

// ---------------- helpers ----------------
__device__ __forceinline__ float wave_allsum(float v){
  #pragma unroll
  for (int off=32; off; off>>=1) v += __shfl_xor(v, off, 64);
  return v;
}
__device__ __forceinline__ float wave_allmax(float v){
  #pragma unroll
  for (int off=32; off; off>>=1) v = fmaxf(v, __shfl_xor(v, off, 64));
  return v;
}
__device__ __forceinline__ float block_allsum(float v, float* red){
  int t = threadIdx.x;
  v = wave_allsum(v);
  __syncthreads();
  if ((t & 63) == 0) red[t >> 6] = v;
  __syncthreads();
  return red[0] + red[1] + red[2] + red[3];
}
__device__ __forceinline__ float gelu_exact(float x){
  return 0.5f * x * (1.0f + erff(x * 0.70710678118654752f));
}
__device__ __forceinline__ float leaky02(float x){
  return x >= 0.f ? x : 0.2f * x;
}
__device__ __forceinline__ unsigned short f2bf(float f){
  unsigned int u = __float_as_uint(f);
  unsigned int r = (u + 0x7FFFu + ((u >> 16) & 1u)) >> 16;
  return (unsigned short)r;
}

// ---------------- weight transpose + bf16 convert: BT[n][k] = B[k][n] ----------------
__global__ __launch_bounds__(256) void transpose_w(const float* __restrict__ B,
    unsigned short* __restrict__ BT, int K, int N){
  __shared__ float tl[32][33];
  int n0 = blockIdx.x * 32, k0 = blockIdx.y * 32;
  int tx = threadIdx.x & 31, ty = threadIdx.x >> 5;  // ty 0..7
  #pragma unroll
  for (int q = 0; q < 4; q++){
    int k = ty + q*8;
    tl[k][tx] = B[(size_t)(k0 + k) * N + n0 + tx];
  }
  __syncthreads();
  #pragma unroll
  for (int q = 0; q < 4; q++){
    int n = ty + q*8;
    BT[(size_t)(n0 + n) * K + k0 + tx] = f2bf(tl[tx][n]);
  }
}

// ---------------- bf16 MFMA GEMM: C[M,N] = (ACC? C:0) + A[M,K] @ BT[N,K]^T ----------------
// A is f32 (converted to bf16 during staging); BT is pre-converted bf16 bits.
// Tile 128x64, BK=32, 256 threads = 4 waves; each wave: 32 rows x 64 cols
// = 2 row-subtiles x 4 col-tiles of 16x16, via v_mfma_f32_16x16x32_bf16.
template<bool ACC>
__global__ __launch_bounds__(256) void gemm_bf16(const float* __restrict__ A,
    const unsigned short* __restrict__ BT, float* __restrict__ C,
    int M, int Nc, int K){
  __shared__ unsigned short As[128][40];  // +8 pad: frag reads 2-way (free)
  __shared__ unsigned short Bs[64][40];
  int t = threadIdx.x;
  int m0 = blockIdx.y * 128, n0 = blockIdx.x * 64;
  int wave = t >> 6, lane = t & 63;
  int fr = lane & 15, fs = lane >> 4;
  f32x4 acc[2][4] = {};

  int ra = t >> 2, sa = t & 3;  // A/B staging: row, k-segment(8 bf16)
  for (int k0 = 0; k0 < K; k0 += 32){
    __syncthreads();
    // stage A rows ra and ra+64 (convert f32->bf16)
    {
      const float* p = &A[(size_t)(m0 + ra) * K + k0 + sa*8];
      f32x4 u0 = *(const f32x4*)p;
      f32x4 u1 = *(const f32x4*)(p + 4);
      u16x8 w;
      #pragma unroll
      for (int i = 0; i < 4; i++){ w[i] = f2bf(u0[i]); w[4+i] = f2bf(u1[i]); }
      *(u16x8*)&As[ra][sa*8] = w;
      p = &A[(size_t)(m0 + 64 + ra) * K + k0 + sa*8];
      u0 = *(const f32x4*)p;
      u1 = *(const f32x4*)(p + 4);
      #pragma unroll
      for (int i = 0; i < 4; i++){ w[i] = f2bf(u0[i]); w[4+i] = f2bf(u1[i]); }
      *(u16x8*)&As[64 + ra][sa*8] = w;
    }
    // stage BT rows (n-major, k contiguous) — already bf16
    *(u16x8*)&Bs[ra][sa*8] = *(const u16x8*)&BT[(size_t)(n0 + ra) * K + k0 + sa*8];
    __syncthreads();

    bf16x8 a0 = *(const bf16x8*)&As[wave*32 + fr][fs*8];
    bf16x8 a1 = *(const bf16x8*)&As[wave*32 + 16 + fr][fs*8];
    #pragma unroll
    for (int c = 0; c < 4; c++){
      bf16x8 b = *(const bf16x8*)&Bs[c*16 + fr][fs*8];
      acc[0][c] = __builtin_amdgcn_mfma_f32_16x16x32_bf16(a0, b, acc[0][c], 0, 0, 0);
      acc[1][c] = __builtin_amdgcn_mfma_f32_16x16x32_bf16(a1, b, acc[1][c], 0, 0, 0);
    }
  }
  // C/D layout (verified): col = lane&15, row = (lane>>4)*4 + reg
  #pragma unroll
  for (int sub = 0; sub < 2; sub++){
    #pragma unroll
    for (int c = 0; c < 4; c++){
      #pragma unroll
      for (int i = 0; i < 4; i++){
        int m = m0 + wave*32 + sub*16 + fs*4 + i;
        int n = n0 + c*16 + fr;
        size_t idx = (size_t)m * Nc + n;
        C[idx] = (ACC ? C[idx] : 0.0f) + acc[sub][c][i];
      }
    }
  }
}

// ---------------- x finalize: x = mask ? mask_token : 0.5*(tmp + bv + bt) ----------------
__global__ void xfin_kernel(const float* __restrict__ tmp, const float* __restrict__ pvb,
                            const float* __restrict__ ptb, const float* __restrict__ mtok,
                            const int* __restrict__ mask_int, float* __restrict__ x){
  int i = blockIdx.x * 256 + threadIdx.x;
  int n = i >> 8, j = i & 255;
  bool m = (mask_int[n] == 0);
  x[i] = m ? mtok[j] : 0.5f * (tmp[i] + pvb[j] + ptb[j]);
}

__global__ void mlist_kernel(const int* __restrict__ mask_int, int* mlist, int* mcount){
  int n = blockIdx.x * 256 + threadIdx.x;
  if (n < NN && mask_int[n] == 0){
    int p = atomicAdd(mcount, 1);
    mlist[p] = n;
  }
}

// ---------------- gate: softmax over 8, top-2 ----------------
__global__ __launch_bounds__(256) void gate_topk_kernel(const float* __restrict__ x,
    const float* __restrict__ gw, const float* __restrict__ gb,
    int* __restrict__ ti, float* __restrict__ twt){
  int n = blockIdx.x, t = threadIdx.x;
  __shared__ float sx[256];
  __shared__ float logits[8];
  sx[t] = x[(size_t)n*256 + t];
  __syncthreads();
  int e = t >> 5, lane = t & 31;
  float p = 0.f;
  for (int h2 = lane; h2 < 256; h2 += 32) p += sx[h2] * gw[h2*8 + e];
  #pragma unroll
  for (int off = 16; off; off >>= 1) p += __shfl_down(p, off, 32);
  if (lane == 0) logits[e] = p + gb[e];
  __syncthreads();
  if (t == 0){
    float mx = -3.0e38f;
    #pragma unroll
    for (int i = 0; i < 8; i++) mx = fmaxf(mx, logits[i]);
    float g[8], s = 0.f;
    #pragma unroll
    for (int i = 0; i < 8; i++){ g[i] = expf(logits[i] - mx); s += g[i]; }
    #pragma unroll
    for (int i = 0; i < 8; i++) g[i] /= s;
    int i0 = 0;
    for (int i = 1; i < 8; i++) if (g[i] > g[i0]) i0 = i;
    int i1 = (i0 == 0) ? 1 : 0;
    for (int i = 0; i < 8; i++) if (i != i0 && g[i] > g[i1]) i1 = i;
    float w0 = g[i0], w1 = g[i1], sw = w0 + w1;
    ti[n*2] = i0; ti[n*2+1] = i1;
    twt[n*2] = w0 / sw; twt[n*2+1] = w1 / sw;
  }
}

// ---------------- MoE: per node, 2 selected experts (GEMV+LN+GELU+GEMV) ----------------
__global__ __launch_bounds__(256) void moe_kernel(const float* __restrict__ x,
    const int* __restrict__ ti, const float* __restrict__ twt,
    const float* __restrict__ w1, const float* __restrict__ b1,
    const float* __restrict__ lng, const float* __restrict__ lnb,
    const float* __restrict__ w2, const float* __restrict__ b2,
    float* __restrict__ h){
  int n = blockIdx.x, t = threadIdx.x;
  __shared__ float sx[256], sh[256];
  __shared__ float red[4];
  sx[t] = x[(size_t)n*256 + t];
  float acc = 0.f;
  for (int k = 0; k < 2; k++){
    int e = ti[n*2 + k];
    float wgt = twt[n*2 + k];
    const float* W1 = w1 + (size_t)e * 65536;
    const float* W2 = w2 + (size_t)e * 65536;
    __syncthreads();
    float s = b1[e*256 + t];
    for (int hh = 0; hh < 256; hh++) s += sx[hh] * W1[hh*256 + t];
    float mean = block_allsum(s, red) * (1.f/256.f);
    float d = s - mean;
    float var = block_allsum(d*d, red) * (1.f/256.f);
    float nrm = d * rsqrtf(var + 1e-5f) * lng[e*256 + t] + lnb[e*256 + t];
    float ge = gelu_exact(nrm);
    __syncthreads();
    sh[t] = ge;
    __syncthreads();
    float o = b2[e*256 + t];
    for (int kk = 0; kk < 256; kk++) o += sh[kk] * W2[kk*256 + t];
    acc += wgt * o;
  }
  h[(size_t)n*256 + t] = acc;
}

// ---------------- CSR build ----------------
__global__ void csr_count(const int* __restrict__ dst, int* counts){
  int e = blockIdx.x * 256 + threadIdx.x;
  if (e < EE) atomicAdd(&counts[dst[e]], 1);
}
__global__ __launch_bounds__(1024) void csr_scan(const int* __restrict__ counts, int* offs){
  __shared__ int part[1024];
  int t = threadIdx.x;
  int base = t * 6;
  int c[6]; int s = 0;
  #pragma unroll
  for (int q = 0; q < 6; q++){ c[q] = counts[base + q]; s += c[q]; }
  part[t] = s;
  __syncthreads();
  for (int off = 1; off < 1024; off <<= 1){
    int add = (t >= off) ? part[t - off] : 0;
    __syncthreads();
    part[t] += add;
    __syncthreads();
  }
  int excl = (t == 0) ? 0 : part[t-1];
  #pragma unroll
  for (int q = 0; q < 6; q++){ offs[base + q] = excl; excl += c[q]; }
  if (t == 1023) offs[NN] = excl;
}
__global__ void csr_fill(const int* __restrict__ src, const int* __restrict__ dst,
                         const int* __restrict__ offs, int* cursors, int* esrc){
  int e = blockIdx.x * 256 + threadIdx.x;
  if (e < EE){
    int d = dst[e];
    int pos = offs[d] + atomicAdd(&cursors[d], 1);
    esrc[pos] = src[e];
  }
}

// ---------------- GAT: el/er ----------------
__global__ __launch_bounds__(256) void eler_kernel(const float* __restrict__ z,
    const float* __restrict__ al, const float* __restrict__ ar,
    float* __restrict__ el, float* __restrict__ er){
  int n = blockIdx.x, t = threadIdx.x;
  int hd = t >> 6, lane = t & 63;
  const float* zr = z + (size_t)n*1024 + hd*256;
  float pl = 0.f, pr = 0.f;
  #pragma unroll
  for (int q = 0; q < 4; q++){
    int j = lane + q*64;
    float zv = zr[j];
    pl += zv * al[hd*256 + j];
    pr += zv * ar[hd*256 + j];
  }
  pl = wave_allsum(pl);
  pr = wave_allsum(pr);
  if (lane == 0){ el[n*4 + hd] = pl; er[n*4 + hd] = pr; }
}

// ---------------- GAT: per-dst softmax-aggregate ----------------
__global__ __launch_bounds__(256) void gat_agg(const float* __restrict__ z,
    const float* __restrict__ el, const float* __restrict__ er,
    const int* __restrict__ offs, const int* __restrict__ esrc,
    const float* __restrict__ bias, float* __restrict__ hout){
  int n = blockIdx.x, t = threadIdx.x;
  int beg = offs[n], end = offs[n+1], deg = end - beg;
  __shared__ float ser[4];
  __shared__ float rbuf[4][4];
  __shared__ float smax[4], sden[4];
  __shared__ int ssrc[64];
  __shared__ float sal[64][4];
  if (t < 4) ser[t] = er[n*4 + t];
  __syncthreads();
  float acc4[4] = {0.f, 0.f, 0.f, 0.f};
  if (deg > 0){
    float mx[4] = {-3.0e38f, -3.0e38f, -3.0e38f, -3.0e38f};
    for (int i = t; i < deg; i += 256){
      int s = esrc[beg + i];
      #pragma unroll
      for (int hd = 0; hd < 4; hd++){
        float ev = leaky02(el[s*4 + hd] + ser[hd]);
        mx[hd] = fmaxf(mx[hd], ev);
      }
    }
    #pragma unroll
    for (int hd = 0; hd < 4; hd++) mx[hd] = wave_allmax(mx[hd]);
    if ((t & 63) == 0){
      #pragma unroll
      for (int hd = 0; hd < 4; hd++) rbuf[t >> 6][hd] = mx[hd];
    }
    __syncthreads();
    if (t < 4) smax[t] = fmaxf(fmaxf(rbuf[0][t], rbuf[1][t]), fmaxf(rbuf[2][t], rbuf[3][t]));
    __syncthreads();
    float sum_[4] = {0.f, 0.f, 0.f, 0.f};
    for (int i = t; i < deg; i += 256){
      int s = esrc[beg + i];
      #pragma unroll
      for (int hd = 0; hd < 4; hd++){
        float ev = leaky02(el[s*4 + hd] + ser[hd]);
        sum_[hd] += expf(ev - smax[hd]);
      }
    }
    #pragma unroll
    for (int hd = 0; hd < 4; hd++) sum_[hd] = wave_allsum(sum_[hd]);
    if ((t & 63) == 0){
      #pragma unroll
      for (int hd = 0; hd < 4; hd++) rbuf[t >> 6][hd] = sum_[hd];
    }
    __syncthreads();
    if (t < 4){
      float den = rbuf[0][t] + rbuf[1][t] + rbuf[2][t] + rbuf[3][t];
      sden[t] = (den > 0.f) ? 1.f / den : 1.f;
    }
    __syncthreads();
    for (int base = 0; base < deg; base += 64){
      int cnt = min(64, deg - base);
      __syncthreads();
      if (t < cnt){
        int s = esrc[beg + base + t];
        ssrc[t] = s;
        #pragma unroll
        for (int hd = 0; hd < 4; hd++){
          float ev = leaky02(el[s*4 + hd] + ser[hd]);
          sal[t][hd] = expf(ev - smax[hd]) * sden[hd];
        }
      }
      __syncthreads();
      for (int i = 0; i < cnt; i++){
        const float* zp = z + (size_t)ssrc[i] * 1024;
        #pragma unroll
        for (int hd = 0; hd < 4; hd++) acc4[hd] += sal[i][hd] * zp[hd*256 + t];
      }
    }
  }
  float o = 0.f;
  #pragma unroll
  for (int hd = 0; hd < 4; hd++) o += acc4[hd] + bias[hd*256 + t];
  hout[(size_t)n*256 + t] = 0.25f * o;
}

// ---------------- recon loss for masked nodes ----------------
__global__ __launch_bounds__(256) void rec_kernel(const float* __restrict__ h,
    const int* __restrict__ mlist, const int* __restrict__ mcount,
    const float* __restrict__ w1, const float* __restrict__ b1,
    const float* __restrict__ g, const float* __restrict__ bb,
    const float* __restrict__ w2, const float* __restrict__ b2,
    const float* __restrict__ tgt, int Vd, float* __restrict__ acc_out){
  int idx = blockIdx.x;
  if (idx >= *mcount) return;
  int n = mlist[idx];
  int t = threadIdx.x;
  __shared__ float sx[256], sh[256];
  __shared__ float red[4];
  sx[t] = h[(size_t)n*256 + t];
  __syncthreads();
  float s = b1[t];
  for (int hh = 0; hh < 256; hh++) s += sx[hh] * w1[hh*256 + t];
  float mean = block_allsum(s, red) * (1.f/256.f);
  float d = s - mean;
  float var = block_allsum(d*d, red) * (1.f/256.f);
  float nrm = d * rsqrtf(var + 1e-5f) * g[t] + bb[t];
  float ge = gelu_exact(nrm);
  __syncthreads();
  sh[t] = ge;
  __syncthreads();
  float dot = 0.f, nr = 0.f, nt = 0.f;
  for (int j = t; j < Vd; j += 256){
    float r = b2[j];
    for (int k = 0; k < 256; k++) r += sh[k] * w2[(size_t)k*Vd + j];
    float tg = tgt[(size_t)n*Vd + j];
    dot += r * tg; nr += r * r; nt += tg * tg;
  }
  dot = block_allsum(dot, red);
  __syncthreads();
  nr = block_allsum(nr, red);
  __syncthreads();
  nt = block_allsum(nt, red);
  if (t == 0){
    float sim = dot / (fmaxf(sqrtf(nr), 1e-8f) * fmaxf(sqrtf(nt), 1e-8f));
    float f = 1.f - sim;
    atomicAdd(acc_out, f * f);
  }
}

// ---------------- SPD: li/lj ----------------
__global__ __launch_bounds__(256) void spd_lin_kernel(const float* __restrict__ h,
    const int* __restrict__ sidx, const float* __restrict__ w1,
    float* __restrict__ li, float* __restrict__ lj){
  int i = blockIdx.x, t = threadIdx.x;
  __shared__ float sx[256];
  int n = sidx[i];
  sx[t] = h[(size_t)n*256 + t];
  __syncthreads();
  float a = 0.f, b = 0.f;
  for (int hh = 0; hh < 256; hh++){
    float xv = sx[hh];
    a += xv * w1[hh*256 + t];
    b += xv * w1[(256 + hh)*256 + t];
  }
  li[i*256 + t] = a;
  lj[i*256 + t] = b;
}

// ---------------- SPD: pairwise LN+GELU+dot, MSE accumulate ----------------
__global__ __launch_bounds__(256) void spd_pair_kernel(const float* __restrict__ li,
    const float* __restrict__ lj, const float* __restrict__ b1,
    const float* __restrict__ lng, const float* __restrict__ lnb,
    const float* __restrict__ w2, const float* __restrict__ b2,
    const float* __restrict__ spd, const int* __restrict__ sidx,
    float* __restrict__ buckets){
  int wid = threadIdx.x >> 6, lane = threadIdx.x & 63;
  int pair = blockIdx.x * 4 + wid;
  int i = pair / SS, j = pair % SS;
  __shared__ float bsum[4];
  float v[4];
  float tot = 0.f;
  #pragma unroll
  for (int q = 0; q < 4; q++){
    int c = lane + q*64;
    v[q] = li[i*256 + c] + lj[j*256 + c] + b1[c];
    tot += v[q];
  }
  tot = wave_allsum(tot);
  float mean = tot * (1.f/256.f);
  float var = 0.f;
  #pragma unroll
  for (int q = 0; q < 4; q++){ float d = v[q] - mean; var += d*d; }
  var = wave_allsum(var) * (1.f/256.f);
  float rstd = rsqrtf(var + 1e-5f);
  float dotp = 0.f;
  #pragma unroll
  for (int q = 0; q < 4; q++){
    int c = lane + q*64;
    float nrm = (v[q] - mean) * rstd * lng[c] + lnb[c];
    dotp += gelu_exact(nrm) * w2[c];
  }
  dotp = wave_allsum(dotp);
  float contrib = 0.f;
  if (lane == 0){
    float pred = dotp + b2[0];
    float st = spd[(size_t)sidx[i] * NN + sidx[j]];
    float diff = pred - st;
    contrib = diff * diff;
  }
  if (lane == 0) bsum[wid] = contrib;
  __syncthreads();
  if (threadIdx.x == 0){
    float s = bsum[0] + bsum[1] + bsum[2] + bsum[3];
    atomicAdd(&buckets[blockIdx.x & 255], s);
  }
}

// ---------------- finalize ----------------
__global__ __launch_bounds__(256) void finalize_kernel(const float* __restrict__ rec_acc,
    const float* __restrict__ buckets, const int* __restrict__ mcount,
    float* __restrict__ out){
  __shared__ float red[4];
  int t = threadIdx.x;
  float v = buckets[t];
  float spd_sum = block_allsum(v, red);
  if (t == 0){
    float nm = fmaxf((float)(*mcount), 1.0f);
    out[0] = rec_acc[0] / nm + 0.5f * (spd_sum / (float)(SS * SS));
  }
}

__global__ void copy_h_kernel(const float* __restrict__ h, float* __restrict__ out){
  int i = blockIdx.x * 256 + threadIdx.x;
  out[1 + i] = h[i];
}

// ---------------- launch ----------------
extern "C" void kernel_launch(void* const* d_in, const int* in_sizes, int n_in,
                              void* d_out, int out_size, void* d_ws, size_t ws_size,
                              hipStream_t stream){
  const float* feat_v   = (const float*)d_in[0];
  const float* feat_t   = (const float*)d_in[1];
  const float* spd_mat  = (const float*)d_in[2];
  const float* proj_v_w = (const float*)d_in[3];
  const float* proj_v_b = (const float*)d_in[4];
  const float* proj_t_w = (const float*)d_in[5];
  const float* proj_t_b = (const float*)d_in[6];
  const float* mask_tok = (const float*)d_in[7];
  const float* gate_w   = (const float*)d_in[8];
  const float* gate_b   = (const float*)d_in[9];
  const float* moe_w1   = (const float*)d_in[10];
  const float* moe_b1   = (const float*)d_in[11];
  const float* moe_lng  = (const float*)d_in[12];
  const float* moe_lnb  = (const float*)d_in[13];
  const float* moe_w2   = (const float*)d_in[14];
  const float* moe_b2   = (const float*)d_in[15];
  const float* gat_fc   = (const float*)d_in[16];
  const float* gat_al   = (const float*)d_in[17];
  const float* gat_ar   = (const float*)d_in[18];
  const float* gat_bias = (const float*)d_in[19];
  const float* dv_w1 = (const float*)d_in[20];
  const float* dv_b1 = (const float*)d_in[21];
  const float* dv_g  = (const float*)d_in[22];
  const float* dv_b  = (const float*)d_in[23];
  const float* dv_w2 = (const float*)d_in[24];
  const float* dv_b2 = (const float*)d_in[25];
  const float* dt_w1 = (const float*)d_in[26];
  const float* dt_b1 = (const float*)d_in[27];
  const float* dt_g  = (const float*)d_in[28];
  const float* dt_b  = (const float*)d_in[29];
  const float* dt_w2 = (const float*)d_in[30];
  const float* dt_b2 = (const float*)d_in[31];
  const float* spd_w1 = (const float*)d_in[32];
  const float* spd_b1 = (const float*)d_in[33];
  const float* spd_g  = (const float*)d_in[34];
  const float* spd_bb = (const float*)d_in[35];
  const float* spd_w2 = (const float*)d_in[36];
  const float* spd_b2 = (const float*)d_in[37];
  const int* src      = (const int*)d_in[38];
  const int* dst      = (const int*)d_in[39];
  const int* mask_int = (const int*)d_in[40];
  const int* sidx     = (const int*)d_in[41];

  // workspace carve (256B aligned)
  char* ws = (char*)d_ws;
  size_t off = 0;
  auto carve = [&](size_t bytes) -> char* {
    char* p = ws + off;
    off = (off + bytes + 255) & ~(size_t)255;
    return p;
  };
  // control block (memset to 0 each launch)
  int* counts  = (int*)carve(NN * 4);
  int* cursors = (int*)carve(NN * 4);
  int* offs    = (int*)carve((NN + 1) * 4);
  int* mlist   = (int*)carve(NN * 4);
  int* mcount  = (int*)carve(4);
  float* rec_acc = (float*)carve(4);
  float* buckets = (float*)carve(256 * 4);
  int* esrc    = (int*)carve(EE * 4);
  int* ti      = (int*)carve(NN * 2 * 4);
  size_t ctl_bytes = off;
  float* twt = (float*)carve(NN * 2 * 4);
  float* tmp = (float*)carve((size_t)NN * HH * 4);
  float* x   = (float*)carve((size_t)NN * HH * 4);
  float* hA  = (float*)carve((size_t)NN * HH * 4);
  float* hB  = (float*)carve((size_t)NN * HH * 4);
  float* z   = (float*)carve((size_t)NN * NHEADS * HH * 4);
  float* el  = (float*)carve((size_t)NN * NHEADS * 4);
  float* er  = (float*)carve((size_t)NN * NHEADS * 4);
  float* li  = (float*)carve((size_t)SS * HH * 4);
  float* lj  = (float*)carve((size_t)SS * HH * 4);
  unsigned short* projvBT = (unsigned short*)carve((size_t)HH * VV * 2);       // [256][1024]
  unsigned short* projtBT = (unsigned short*)carve((size_t)HH * TT * 2);       // [256][768]
  unsigned short* gatBT   = (unsigned short*)carve((size_t)3 * NHEADS*HH * HH * 2); // 3x[1024][256]
  (void)ws_size; (void)in_sizes; (void)n_in; (void)out_size;

  hipMemsetAsync(ws, 0, ctl_bytes, stream);

  // weight transposes -> bf16 BT[N][K]
  transpose_w<<<dim3(HH/32, VV/32), 256, 0, stream>>>(proj_v_w, projvBT, VV, HH);
  transpose_w<<<dim3(HH/32, TT/32), 256, 0, stream>>>(proj_t_w, projtBT, TT, HH);
  for (int l = 0; l < 3; l++)
    transpose_w<<<dim3(NHEADS*HH/32, HH/32), 256, 0, stream>>>(
        gat_fc + (size_t)l * HH * NHEADS * HH, gatBT + (size_t)l * NHEADS*HH * HH, HH, NHEADS*HH);

  // projection: tmp = feat_v@Wv + feat_t@Wt (bf16 MFMA)
  gemm_bf16<false><<<dim3(HH/64, NN/128), 256, 0, stream>>>(feat_v, projvBT, tmp, NN, HH, VV);
  gemm_bf16<true ><<<dim3(HH/64, NN/128), 256, 0, stream>>>(feat_t, projtBT, tmp, NN, HH, TT);
  xfin_kernel<<<NN * HH / 256, 256, 0, stream>>>(tmp, proj_v_b, proj_t_b, mask_tok, mask_int, x);
  mlist_kernel<<<NN / 256, 256, 0, stream>>>(mask_int, mlist, mcount);

  // MoE
  gate_topk_kernel<<<NN, 256, 0, stream>>>(x, gate_w, gate_b, ti, twt);
  moe_kernel<<<NN, 256, 0, stream>>>(x, ti, twt, moe_w1, moe_b1, moe_lng, moe_lnb,
                                     moe_w2, moe_b2, hA);

  // CSR by dst
  csr_count<<<EE / 256, 256, 0, stream>>>(dst, counts);
  csr_scan<<<1, 1024, 0, stream>>>(counts, offs);
  csr_fill<<<EE / 256, 256, 0, stream>>>(src, dst, offs, cursors, esrc);

  // GAT layers
  float* hin = hA; float* hout_ = hB;
  for (int l = 0; l < 3; l++){
    gemm_bf16<false><<<dim3(NHEADS*HH/64, NN/128), 256, 0, stream>>>(
        hin, gatBT + (size_t)l * NHEADS*HH * HH, z, NN, NHEADS*HH, HH);
    eler_kernel<<<NN, 256, 0, stream>>>(z, gat_al + (size_t)l * NHEADS * HH,
                                        gat_ar + (size_t)l * NHEADS * HH, el, er);
    gat_agg<<<NN, 256, 0, stream>>>(z, el, er, offs, esrc,
                                    gat_bias + (size_t)l * NHEADS * HH, hout_);
    float* sw = hin; hin = hout_; hout_ = sw;
  }
  // hin now holds final h

  // recon losses (masked nodes only)
  rec_kernel<<<NN, 256, 0, stream>>>(hin, mlist, mcount, dv_w1, dv_b1, dv_g, dv_b,
                                     dv_w2, dv_b2, feat_v, VV, rec_acc);
  rec_kernel<<<NN, 256, 0, stream>>>(hin, mlist, mcount, dt_w1, dt_b1, dt_g, dt_b,
                                     dt_w2, dt_b2, feat_t, TT, rec_acc);

  // SPD loss
  spd_lin_kernel<<<SS, 256, 0, stream>>>(hin, sidx, spd_w1, li, lj);
  spd_pair_kernel<<<SS * SS / 4, 256, 0, stream>>>(li, lj, spd_b1, spd_g, spd_bb,
                                                   spd_w2, spd_b2, spd_mat, sidx, buckets);

  finalize_kernel<<<1, 256, 0, stream>>>(rec_acc, buckets, mcount, (float*)d_out);
  copy_h_kernel<<<NN * HH / 256, 256, 0, stream>>>(hin, (float*)d_out);
}